// Round 3
// baseline (271.969 us; speedup 1.0000x reference)
//
#include <hip/hip_runtime.h>
#include <stdint.h>

typedef _Float16 half8 __attribute__((ext_vector_type(8)));
typedef _Float16 half4v __attribute__((ext_vector_type(4)));
typedef float floatx4 __attribute__((ext_vector_type(4)));
typedef float floatx16 __attribute__((ext_vector_type(16)));

#define TT 4096
#define DH 512

#define WAITVM(n) asm volatile("s_waitcnt vmcnt(" #n ")" ::: "memory")
#define WAITLGKM() asm volatile("s_waitcnt lgkmcnt(0)" ::: "memory")
#define BAR() __builtin_amdgcn_s_barrier()

__device__ __forceinline__ unsigned short f2h(float f) {
    union { _Float16 h; unsigned short u; } v;
    v.h = (_Float16)f;
    return v.u;
}

// ---------- kernel 1: normalize right half of x -> xn (fp16), one wave per row ----------
__global__ void norm_k(const float* __restrict__ x, unsigned short* __restrict__ xn) {
    const int w = threadIdx.x >> 6, l = threadIdx.x & 63;
    const int row = blockIdx.x * 4 + w;              // 0 .. B*T-1
    const float* src = x + (size_t)row * 1024 + 512 + l * 8;
    floatx4 a = *(const floatx4*)src;
    floatx4 c = *(const floatx4*)(src + 4);
    float s = a[0]*a[0] + a[1]*a[1] + a[2]*a[2] + a[3]*a[3]
            + c[0]*c[0] + c[1]*c[1] + c[2]*c[2] + c[3]*c[3];
    #pragma unroll
    for (int off = 32; off > 0; off >>= 1) s += __shfl_xor(s, off);
    const float scale = 1.0f / fmaxf(sqrtf(s), 1e-12f);
    float v[8] = {a[0], a[1], a[2], a[3], c[0], c[1], c[2], c[3]};
    uint32_t pk[4];
    #pragma unroll
    for (int i = 0; i < 4; i++)
        pk[i] = (uint32_t)f2h(v[2*i] * scale) | ((uint32_t)f2h(v[2*i+1] * scale) << 16);
    uint4 o; o.x = pk[0]; o.y = pk[1]; o.z = pk[2]; o.w = pk[3];
    *(uint4*)(xn + (size_t)row * DH + l * 8) = o;
}

// ---------- kernel 2: xnT[b][d][t] = xn[b][t][d], 64x64 LDS tile transpose ----------
__global__ void transpose_k(const unsigned short* __restrict__ xn,
                            unsigned short* __restrict__ xnT) {
    __shared__ __align__(16) unsigned short tile[64 * 72];  // +8 pad
    const int b = blockIdx.z;
    const int t0 = blockIdx.x * 64, d0 = blockIdx.y * 64;
    const int tid = threadIdx.x;
    #pragma unroll
    for (int i = 0; i < 2; i++) {
        int c = i * 256 + tid;
        int tr = c >> 3, d8 = c & 7;
        uint4 vv = *(const uint4*)(xn + ((size_t)(b * TT + t0 + tr) * DH + d0 + d8 * 8));
        *(uint4*)&tile[tr * 72 + d8 * 8] = vv;
    }
    __syncthreads();
    #pragma unroll
    for (int i = 0; i < 2; i++) {
        int c = i * 256 + tid;
        int dd = c >> 3, t8 = c & 7;
        uint32_t pk[4];
        #pragma unroll
        for (int k = 0; k < 4; k++) {
            uint32_t h0 = tile[(t8 * 8 + 2 * k    ) * 72 + dd];
            uint32_t h1 = tile[(t8 * 8 + 2 * k + 1) * 72 + dd];
            pk[k] = h0 | (h1 << 16);
        }
        uint4 o; o.x = pk[0]; o.y = pk[1]; o.z = pk[2]; o.w = pk[3];
        *(uint4*)(xnT + ((size_t)(b * DH + d0 + dd) * TT + t0 + t8 * 8)) = o;
    }
}

// ---------- kernel 3: fused  ctx = (V .* (Q Kn^T)) Kn ;  out = x_left * sigmoid(ctx+bias) ----------
// 512 threads = 8 waves.
// s1 roles: wave = (mi = w&1, ni = (w>>1)&1, dh = w>>2): one 32x32 S^T tile over K=256.
// s3/epilogue roles: wave w owns d-slice [w*64, w*64+64), B-fragments (kt) in REGISTERS.
// LDS: knL double-buffered 2x64 KiB | Sred [2][64][64] fp16 16 KiB | W [64][72] fp16 9 KiB.
// 3 barriers/tile; kn staged via global_load_lds a full tile ahead (counted vmcnt).
__global__ __launch_bounds__(512, 2) void fused_k(
    const unsigned short* __restrict__ xn, const unsigned short* __restrict__ xnT,
    const float* __restrict__ V, const float* __restrict__ bias,
    const float* __restrict__ x, float* __restrict__ out)
{
    __shared__ __align__(16) unsigned short smem[78336];   // 153 KiB
    unsigned short* SredL = smem + 65536;
    unsigned short* Wl    = smem + 73728;

    const int tid = threadIdx.x;
    const int w = tid >> 6, l = tid & 63;
    const int h = l >> 5, m32 = l & 31;
    const int mi = w & 1, ni = (w >> 1) & 1, dh = w >> 2;

    // XCD-aware swizzle: 256 blocks -> XCD j gets 32 consecutive works (same batch)
    const int flat = blockIdx.y * 64 + blockIdx.x;
    const int work = (flat & 7) * 32 + (flat >> 3);
    const int b = work >> 6, qt = work & 63;
    const int q0 = qt * 64;

    const unsigned short* xnb = xn  + (size_t)b * TT * DH;
    const unsigned short* xtb = xnT + (size_t)b * DH * TT;

    const int tq = tid >> 3, to = tid & 7;
    const float* vrow = V + (size_t)(q0 + tq) * TT + to * 8;

    // ---- prologue: Q fragments (B-operand for s1). lane m32 <-> q, 16 k-slices over dh-half
    half8 qf[16];
    #pragma unroll
    for (int ks = 0; ks < 16; ks++)
        qf[ks] = *(const half8*)(xnb + (size_t)(q0 + ni*32 + m32) * DH + dh*256 + ks*16 + h*8);

    // stage kn[0] into buf0: wave w rows w*8..w*8+7, lds chunk l <- global chunk l^(r&7)
    #pragma unroll
    for (int i = 0; i < 8; i++) {
        int r = w * 8 + i;
        const unsigned short* g = xnb + (size_t)r * DH + ((l ^ (r & 7)) * 8);
        __builtin_amdgcn_global_load_lds(
            (const __attribute__((address_space(1))) void*)g,
            (__attribute__((address_space(3))) void*)&smem[r * 512], 16, 0, 0);
    }
    asm volatile("" ::: "memory");   // pin gll before kt/V in vmcnt issue order

    // kt regs for tile 0: B-frag for s3, lane m32 <-> d col, k-slice kk
    half8 bf[2][4];
    #pragma unroll
    for (int nd = 0; nd < 2; nd++)
        #pragma unroll
        for (int ks = 0; ks < 4; ks++)
            bf[nd][ks] = *(const half8*)(xtb + (size_t)(w*64 + nd*32 + m32) * TT + ks*16 + h*8);
    floatx4 va = *(const floatx4*)(vrow);
    floatx4 vb = *(const floatx4*)(vrow + 4);

    floatx16 acc[2][2];
    #pragma unroll
    for (int i = 0; i < 2; i++)
        #pragma unroll
        for (int j = 0; j < 2; j++)
            acc[i][j] = (floatx16)(0.f);

    #pragma unroll 1
    for (int t = 0; t < 64; t++) {
        // ---- b1: kn[t] landed (kt 8 + V 2 stay in flight) ----
        WAITVM(10);
        BAR();

        // ---- stage kn[t+1] into the other buffer (lands during this whole tile) ----
        if (t < 63) {
            unsigned short* dst = smem + ((t + 1) & 1) * 32768;
            #pragma unroll
            for (int i = 0; i < 8; i++) {
                int r = w * 8 + i;
                const unsigned short* g = xnb + (size_t)((t+1)*64 + r) * DH + ((l ^ (r & 7)) * 8);
                __builtin_amdgcn_global_load_lds(
                    (const __attribute__((address_space(1))) void*)g,
                    (__attribute__((address_space(3))) void*)&dst[r * 512], 16, 0, 0);
            }
        }

        // ---- s1: S^T tile (mi,ni) partial over dh-half, 2 independent mfma chains ----
        const unsigned short* kb = smem + (t & 1) * 32768;
        const int arow = mi * 32 + m32;
        const unsigned short* abase = kb + arow * 512;
        const int asx = arow & 7;
        floatx16 sA = (floatx16)(0.f), sB = (floatx16)(0.f);
        __builtin_amdgcn_s_setprio(1);
        #pragma unroll
        for (int ks = 0; ks < 16; ks += 2) {
            half8 a0 = *(const half8*)&abase[((dh*32 + ks*2     + h) ^ asx) * 8];
            half8 a1 = *(const half8*)&abase[((dh*32 + (ks+1)*2 + h) ^ asx) * 8];
            sA = __builtin_amdgcn_mfma_f32_32x32x16_f16(a0, qf[ks],   sA, 0, 0, 0);
            sB = __builtin_amdgcn_mfma_f32_32x32x16_f16(a1, qf[ks+1], sB, 0, 0, 0);
        }
        __builtin_amdgcn_s_setprio(0);
        floatx16 sacc = sA + sB;

        // ---- Sred write: [dh][q][kk], chunk-of-4 XOR-swizzled by (q&7)<<1 ----
        {
            const int q = ni * 32 + m32;
            const int sw = (q & 7) << 1;
            unsigned short* sb = SredL + dh * 4096 + q * 64;
            #pragma unroll
            for (int rr = 0; rr < 4; rr++) {
                int kk4 = mi * 8 + rr * 2 + h;
                half4v v4;
                v4[0] = (_Float16)sacc[rr*4+0];
                v4[1] = (_Float16)sacc[rr*4+1];
                v4[2] = (_Float16)sacc[rr*4+2];
                v4[3] = (_Float16)sacc[rr*4+3];
                *(half4v*)&sb[(kk4 ^ sw) * 4] = v4;
            }
        }
        WAITLGKM();
        BAR();   // b3: Sred complete

        // ---- reduce 2 partials (pk fp16 adds), multiply V, write W [64][72] ----
        {
            const int ch = (to * 2) ^ ((tq & 7) << 1);
            half8 p0 = *(const half8*)&SredL[tq * 64 + ch * 4];
            half8 p1 = *(const half8*)&SredL[4096 + tq * 64 + ch * 4];
            half8 s = p0 + p1;
            half8 vh;
            vh[0] = (_Float16)va[0]; vh[1] = (_Float16)va[1];
            vh[2] = (_Float16)va[2]; vh[3] = (_Float16)va[3];
            vh[4] = (_Float16)vb[0]; vh[5] = (_Float16)vb[1];
            vh[6] = (_Float16)vb[2]; vh[7] = (_Float16)vb[3];
            half8 wv = s * vh;
            *(half8*)&Wl[tq * 72 + to * 8] = wv;
        }
        WAITLGKM();
        BAR();   // b4: W ready

        // ---- s3: ctx[q][wave d-slice] += W * Kn, B from registers ----
        __builtin_amdgcn_s_setprio(1);
        #pragma unroll
        for (int ks = 0; ks < 4; ks++) {
            half8 wf0 = *(const half8*)&Wl[(m32     ) * 72 + (ks*2 + h) * 8];
            half8 wf1 = *(const half8*)&Wl[(32 + m32) * 72 + (ks*2 + h) * 8];
            acc[0][0] = __builtin_amdgcn_mfma_f32_32x32x16_f16(wf0, bf[0][ks], acc[0][0], 0, 0, 0);
            acc[0][1] = __builtin_amdgcn_mfma_f32_32x32x16_f16(wf0, bf[1][ks], acc[0][1], 0, 0, 0);
            acc[1][0] = __builtin_amdgcn_mfma_f32_32x32x16_f16(wf1, bf[0][ks], acc[1][0], 0, 0, 0);
            acc[1][1] = __builtin_amdgcn_mfma_f32_32x32x16_f16(wf1, bf[1][ks], acc[1][1], 0, 0, 0);
        }
        __builtin_amdgcn_s_setprio(0);

        // ---- prefetch kt/V for t+1 (registers; consumed next tile) ----
        if (t < 63) {
            #pragma unroll
            for (int nd = 0; nd < 2; nd++)
                #pragma unroll
                for (int ks = 0; ks < 4; ks++)
                    bf[nd][ks] = *(const half8*)(xtb + (size_t)(w*64 + nd*32 + m32) * TT
                                                 + (t+1)*64 + ks*16 + h*8);
            va = *(const floatx4*)(vrow + (t+1)*64);
            vb = *(const floatx4*)(vrow + (t+1)*64 + 4);
        }
    }

    // ---- epilogue: out = x_left * sigmoid(ctx + bias) ----
    const float* xb = x + (size_t)b * TT * 1024;
    float* ob = out + (size_t)b * TT * DH;
    #pragma unroll
    for (int mi2 = 0; mi2 < 2; mi2++)
        #pragma unroll
        for (int nd = 0; nd < 2; nd++) {
            int d = w * 64 + nd * 32 + m32;
            float bv = bias[d];
            #pragma unroll
            for (int r = 0; r < 16; r++) {
                int q = q0 + mi2 * 32 + (r & 3) + 8 * (r >> 2) + 4 * h;
                float cv = acc[mi2][nd][r] + bv;
                float gate = 1.0f / (1.0f + __expf(-cv));
                ob[(size_t)q * DH + d] = xb[(size_t)q * 1024 + d] * gate;
            }
        }
}

extern "C" void kernel_launch(void* const* d_in, const int* in_sizes, int n_in,
                              void* d_out, int out_size, void* d_ws, size_t ws_size,
                              hipStream_t stream) {
    const float* x    = (const float*)d_in[0];
    const float* V    = (const float*)d_in[1];
    const float* bias = (const float*)d_in[2];
    float* out = (float*)d_out;

    unsigned short* xn  = (unsigned short*)d_ws;              // [4][4096][512] fp16
    unsigned short* xnT = xn + (size_t)4 * TT * DH;           // [4][512][4096] fp16

    norm_k<<<dim3(4 * TT / 4), 256, 0, stream>>>(x, xn);
    transpose_k<<<dim3(TT / 64, DH / 64, 4), 256, 0, stream>>>(xn, xnT);
    fused_k<<<dim3(TT / 64, 4), 512, 0, stream>>>(xn, xnT, V, bias, x, out);
}